// Round 16
// baseline (998.199 us; speedup 1.0000x reference)
//
#include <hip/hip_runtime.h>

typedef __attribute__((ext_vector_type(8))) short short8;
typedef __attribute__((ext_vector_type(4))) short short4v;
typedef __attribute__((ext_vector_type(4))) float f32x4;
typedef __attribute__((ext_vector_type(16))) float f32x16;
typedef unsigned short u16;

#define Lc 4
#define Dc 1024
#define Hc 16
#define HDc 64
#define DFc 4096
#define Vc 32000
#define Tc 2048

__device__ __forceinline__ u16 f2bf(float f) {
  union { float f; unsigned u; } v; v.f = f;
  return (u16)((v.u + 0x7FFFu + ((v.u >> 16) & 1u)) >> 16);
}

__device__ __forceinline__ void gload_lds16(const u16* g, u16* l) {
  __builtin_amdgcn_global_load_lds(
      (const __attribute__((address_space(1))) unsigned int*)(g),
      (__attribute__((address_space(3))) unsigned int*)(l), 16, 0, 0);
}

#define BARS do { __builtin_amdgcn_s_barrier(); __builtin_amdgcn_sched_barrier(0); } while (0)
#define LGKM(n) do { asm volatile("s_waitcnt lgkmcnt(" #n ")" ::: "memory"); __builtin_amdgcn_sched_barrier(0); } while (0)
#define VMC(n) do { asm volatile("s_waitcnt vmcnt(" #n ")" ::: "memory"); __builtin_amdgcn_sched_barrier(0); } while (0)

// ---------------- f32 -> bf16 cast ----------------
__global__ __launch_bounds__(256) void castk(const float* __restrict__ in, u16* __restrict__ out) {
  size_t i = ((size_t)blockIdx.x * 256 + threadIdx.x) * 4;
  float4 v = *(const float4*)(in + i);
  short4v o; o[0] = f2bf(v.x); o[1] = f2bf(v.y); o[2] = f2bf(v.z); o[3] = f2bf(v.w);
  *(short4v*)(out + i) = o;
}

// ---------------- fused embedding + layernorm ----------------
__global__ __launch_bounds__(256) void embedln(const int* __restrict__ ids, const float* __restrict__ te,
                                               const float* __restrict__ pe, const float* __restrict__ w,
                                               const float* __restrict__ b, float* __restrict__ x,
                                               u16* __restrict__ out) {
  int t = blockIdx.x, tid = threadIdx.x;
  int id = ids[t];
  float4 a = *(const float4*)(te + (size_t)id * Dc + tid * 4);
  float4 p = *(const float4*)(pe + (size_t)t * Dc + tid * 4);
  float4 v; v.x = a.x + p.x; v.y = a.y + p.y; v.z = a.z + p.z; v.w = a.w + p.w;
  size_t i = (size_t)t * Dc + tid * 4;
  *(float4*)(x + i) = v;
  float s = v.x + v.y + v.z + v.w;
  float q = v.x * v.x + v.y * v.y + v.z * v.z + v.w * v.w;
  #pragma unroll
  for (int off = 1; off < 64; off <<= 1) { s += __shfl_xor(s, off); q += __shfl_xor(q, off); }
  __shared__ float red[8];
  if ((tid & 63) == 0) { red[tid >> 6] = s; red[4 + (tid >> 6)] = q; }
  __syncthreads();
  s = red[0] + red[1] + red[2] + red[3];
  q = red[4] + red[5] + red[6] + red[7];
  float mean = s * (1.0f / Dc);
  float rstd = rsqrtf(q * (1.0f / Dc) - mean * mean + 1e-5f);
  float4 wv = *(const float4*)(w + tid * 4);
  float4 bv = *(const float4*)(b + tid * 4);
  out[i + 0] = f2bf((v.x - mean) * rstd * wv.x + bv.x);
  out[i + 1] = f2bf((v.y - mean) * rstd * wv.y + bv.y);
  out[i + 2] = f2bf((v.z - mean) * rstd * wv.z + bv.z);
  out[i + 3] = f2bf((v.w - mean) * rstd * wv.w + bv.w);
}

// ---------------- fused split-K combine + layernorm ----------------
template<int SK>
__global__ __launch_bounds__(256) void combineln(float* __restrict__ x, const float* __restrict__ p,
                                                 const float* __restrict__ bias, const float* __restrict__ w,
                                                 const float* __restrict__ b, u16* __restrict__ out) {
  int t = blockIdx.x, tid = threadIdx.x;
  size_t i = (size_t)t * Dc + tid * 4;
  float4 v = *(const float4*)(x + i);
  #pragma unroll
  for (int s = 0; s < SK; s++) {
    float4 q2 = *(const float4*)(p + (size_t)s * Tc * Dc + i);
    v.x += q2.x; v.y += q2.y; v.z += q2.z; v.w += q2.w;
  }
  float4 bb = *(const float4*)(bias + tid * 4);
  v.x += bb.x; v.y += bb.y; v.z += bb.z; v.w += bb.w;
  *(float4*)(x + i) = v;
  float s = v.x + v.y + v.z + v.w;
  float q = v.x * v.x + v.y * v.y + v.z * v.z + v.w * v.w;
  #pragma unroll
  for (int off = 1; off < 64; off <<= 1) { s += __shfl_xor(s, off); q += __shfl_xor(q, off); }
  __shared__ float red[8];
  if ((tid & 63) == 0) { red[tid >> 6] = s; red[4 + (tid >> 6)] = q; }
  __syncthreads();
  s = red[0] + red[1] + red[2] + red[3];
  q = red[4] + red[5] + red[6] + red[7];
  float mean = s * (1.0f / Dc);
  float rstd = rsqrtf(q * (1.0f / Dc) - mean * mean + 1e-5f);
  float4 wv = *(const float4*)(w + tid * 4);
  float4 bv = *(const float4*)(b + tid * 4);
  out[i + 0] = f2bf((v.x - mean) * rstd * wv.x + bv.x);
  out[i + 1] = f2bf((v.y - mean) * rstd * wv.y + bv.y);
  out[i + 2] = f2bf((v.z - mean) * rstd * wv.z + bv.z);
  out[i + 3] = f2bf((v.w - mean) * rstd * wv.w + bv.w);
}

// ---------------- merged per-layer weight transpose ----------------
__global__ __launch_bounds__(256) void transpose4(const float* __restrict__ qw, const float* __restrict__ ow,
                                                  const float* __restrict__ uw, const float* __restrict__ dw,
                                                  u16* __restrict__ qT, u16* __restrict__ oT,
                                                  u16* __restrict__ uT, u16* __restrict__ dT) {
  __shared__ float tl[32][33];
  int id = blockIdx.x;
  const float* in; u16* out; int R, C, t;
  if (id < 3072)      { in = qw; out = qT; R = Dc;  C = 3 * Dc; t = id; }
  else if (id < 4096) { in = ow; out = oT; R = Dc;  C = Dc;     t = id - 3072; }
  else if (id < 8192) { in = uw; out = uT; R = Dc;  C = DFc;    t = id - 4096; }
  else                { in = dw; out = dT; R = DFc; C = Dc;     t = id - 8192; }
  int tilesX = C >> 5;
  int c0 = (t % tilesX) * 32, r0 = (t / tilesX) * 32;
  int lx = threadIdx.x & 31, ly = threadIdx.x >> 5;
  #pragma unroll
  for (int i = ly; i < 32; i += 8) tl[i][lx] = in[(size_t)(r0 + i) * C + c0 + lx];
  __syncthreads();
  #pragma unroll
  for (int i = ly; i < 32; i += 8) out[(size_t)(c0 + i) * R + r0 + lx] = f2bf(tl[lx][i]);
}

// ---------------- 128x128 layer GEMM, 32x32x16 MFMA, 2-phase counted-lgkm ----------------
// Wave tile 64x64 = 2(tr) x 2(tc) 32x32 tiles. A/B frag: row=lane&31, k=(lane>>5)*8+e.
// C/D: col=lane&31, row=(reg&3)+8*(reg>>2)+4*(lane>>5)  [guide-verified m74/m101].
// EPI: 0 bias->bf16 | 1 bias+silu->bf16 | 4 f32 partial (split-K) | 5 qkv fused (V->vt transposed)
template<int EPI>
__global__ __launch_bounds__(256) void gemm128m(
    const u16* __restrict__ A, const u16* __restrict__ Bt, const float* __restrict__ bias,
    u16* __restrict__ outb, float* __restrict__ outf, int M, int N, int K, int KS) {
  __shared__ __align__(16) u16 lds[32768];
  u16* As = lds;
  u16* Bs = lds + 16384;
  const int NK = KS >> 6;

  int tid = threadIdx.x;
  int w = tid >> 6, lane = tid & 63;
  int l31 = lane & 31, lh = lane >> 5;
  int wr = w >> 1, wc = w & 1;

  int m0 = blockIdx.y * 128, n0 = blockIdx.x * 128;
  int kbase = blockIdx.z * KS;

  int offg[4];
  #pragma unroll
  for (int j = 0; j < 4; j++) {
    int p = tid + j * 256;
    int row = p >> 3;
    int uc = (p & 7) ^ (row & 7);
    offg[j] = row * K + uc * 8;
  }
  const u16* aB = A + (size_t)m0 * K + kbase;
  const u16* bB = Bt + (size_t)n0 * K + kbase;

  auto stA = [&](int kt) {
    u16* l = As + ((kt & 1) << 13) + w * 512;
    #pragma unroll
    for (int j = 0; j < 4; j++)
      gload_lds16(aB + kt * 64 + offg[j], l + j * 2048);
  };
  auto stB = [&](int kt) {
    u16* l = Bs + ((kt & 1) << 13) + w * 512;
    #pragma unroll
    for (int j = 0; j < 4; j++)
      gload_lds16(bB + kt * 64 + offg[j], l + j * 2048);
  };

  // fragment rows (swizzled unit = (ks*2+lh) ^ (row&7))
  int arow0 = wr * 64 + l31;           // tr adds 32
  int brow0 = wc * 64 + l31;           // tc adds 32

  short8 af0[4], af1[4], bf[2][4];

  auto rd_af0 = [&](int slot) {
    const u16* sA = As + (slot << 13);
    #pragma unroll
    for (int ks = 0; ks < 4; ks++) {
      int row = arow0;
      af0[ks] = *(const short8*)(sA + row * 64 + (((ks * 2 + lh) ^ (row & 7))) * 8);
    }
  };
  auto rd_af1 = [&](int slot) {
    const u16* sA = As + (slot << 13);
    #pragma unroll
    for (int ks = 0; ks < 4; ks++) {
      int row = arow0 + 32;
      af1[ks] = *(const short8*)(sA + row * 64 + (((ks * 2 + lh) ^ (row & 7))) * 8);
    }
  };
  auto rd_bf = [&](int slot) {
    const u16* sB = Bs + (slot << 13);
    #pragma unroll
    for (int tc = 0; tc < 2; tc++)
      #pragma unroll
      for (int ks = 0; ks < 4; ks++) {
        int row = brow0 + tc * 32;
        bf[tc][ks] = *(const short8*)(sB + row * 64 + (((ks * 2 + lh) ^ (row & 7))) * 8);
      }
  };

  f32x16 acc[2][2] = {};

  stB(0); stA(0); stB(1);
  VMC(4);
  BARS;
  rd_af0(0);

  for (int kt = 0; kt < NK; ++kt) {
    int slot = kt & 1;
    // ---- PA: issue bf(8)+af1(4); LGKM(4); stage A(kt+1); MFMA tr0 ----
    rd_bf(slot);
    rd_af1(slot);
    LGKM(4);
    BARS;
    if (kt + 1 < NK) stA(kt + 1);
    __builtin_amdgcn_s_setprio(1);
    #pragma unroll
    for (int ks = 0; ks < 4; ks++)
      #pragma unroll
      for (int tc = 0; tc < 2; tc++)
        acc[0][tc] = __builtin_amdgcn_mfma_f32_32x32x16_bf16(af0[ks], bf[tc][ks], acc[0][tc], 0, 0, 0);
    __builtin_amdgcn_s_setprio(0);
    // ---- PB: stage B(kt+2); VMC(4); issue af0(kt+1); LGKM(4); MFMA tr1 ----
    if (kt + 2 < NK) { stB(kt + 2); VMC(4); }
    else if (kt + 1 < NK) { VMC(0); }
    BARS;
    if (kt + 1 < NK) {
      rd_af0((kt + 1) & 1);
      LGKM(4);
    } else {
      LGKM(0);
    }
    __builtin_amdgcn_s_setprio(1);
    #pragma unroll
    for (int ks = 0; ks < 4; ks++)
      #pragma unroll
      for (int tc = 0; tc < 2; tc++)
        acc[1][tc] = __builtin_amdgcn_mfma_f32_32x32x16_bf16(af1[ks], bf[tc][ks], acc[1][tc], 0, 0, 0);
    __builtin_amdgcn_s_setprio(0);
  }

  // ---- epilogues (LDS-coalesced; 32x32 C/D mapping) ----
  if (EPI == 0 || EPI == 1 || (EPI == 5 && n0 < 2 * Dc)) {
    u16* lu = lds;
    BARS;
    #pragma unroll
    for (int tc = 0; tc < 2; tc++) {
      int col = wc * 64 + tc * 32 + l31;
      float bv = bias[n0 + col];
      #pragma unroll
      for (int tr = 0; tr < 2; tr++) {
        #pragma unroll
        for (int reg = 0; reg < 16; reg++) {
          int rl = wr * 64 + tr * 32 + (reg & 3) + 8 * (reg >> 2) + 4 * lh;
          float v = acc[tr][tc][reg] + bv;
          if (EPI == 1) v = v / (1.0f + __expf(-v));
          lu[rl * 128 + (col ^ (((rl >> 2) & 3) << 4))] = f2bf(v);
        }
      }
    }
    BARS;
    #pragma unroll
    for (int j = 0; j < 8; j++) {
      int i8 = j * 2048 + tid * 8;
      int row = i8 >> 7;
      int col8 = i8 & 127;
      short8 v = *(const short8*)(lu + row * 128 + (col8 ^ (((row >> 2) & 3) << 4)));
      *(short8*)(outb + (size_t)(m0 + row) * N + n0 + col8) = v;
    }
  } else if (EPI == 4) {
    float* lf = (float*)lds;
    float* op = outf + (size_t)blockIdx.z * M * N;
    #pragma unroll
    for (int pass = 0; pass < 2; pass++) {
      BARS;
      if (wr == pass) {
        #pragma unroll
        for (int tc = 0; tc < 2; tc++) {
          int col = wc * 64 + tc * 32 + l31;
          #pragma unroll
          for (int tr = 0; tr < 2; tr++)
            #pragma unroll
            for (int reg = 0; reg < 16; reg++) {
              int rl = tr * 32 + (reg & 3) + 8 * (reg >> 2) + 4 * lh;
              lf[rl * 128 + (col ^ (((rl >> 2) & 1) << 4))] = acc[tr][tc][reg];
            }
        }
      }
      BARS;
      #pragma unroll
      for (int j = 0; j < 8; j++) {
        int i4 = j * 1024 + tid * 4;
        int row = i4 >> 7;
        int col4 = i4 & 127;
        f32x4 v = *(const f32x4*)(lf + row * 128 + (col4 ^ (((row >> 2) & 1) << 4)));
        *(f32x4*)(op + (size_t)(m0 + pass * 64 + row) * N + n0 + col4) = v;
      }
    }
  } else {
    // EPI==5 V block (n0 >= 2048): direct transposed write, 4 consecutive rows per reg-group
    u16* vtp = (u16*)outf;
    #pragma unroll
    for (int tc = 0; tc < 2; tc++) {
      int gn = n0 + wc * 64 + tc * 32 + l31;
      float bv = bias[gn];
      #pragma unroll
      for (int tr = 0; tr < 2; tr++) {
        #pragma unroll
        for (int g = 0; g < 4; g++) {
          int gmb = m0 + wr * 64 + tr * 32 + 8 * g + 4 * lh;
          short4v o;
          #pragma unroll
          for (int r = 0; r < 4; r++) o[r] = (short)f2bf(acc[tr][tc][g * 4 + r] + bv);
          *(short4v*)(vtp + (size_t)(gn - 2 * Dc) * Tc + gmb) = o;
        }
      }
    }
  }
}

// ---------------- 256x256 logits GEMM, 32x32x16 MFMA, 2-phase counted-lgkm ----------------
// Wave tile 128x64 = 4(tr) x 2(tc).
__global__ __launch_bounds__(512) void gemm256(const u16* __restrict__ A, const u16* __restrict__ Bt,
                                               float* __restrict__ outf, int M, int N, int K) {
  __shared__ __align__(16) u16 lds[65536];
  u16* AsU = lds;
  u16* BsU = lds + 32768;
  const int NK = K >> 6;

  int tid = threadIdx.x;
  int w = tid >> 6, lane = tid & 63;
  int l31 = lane & 31, lh = lane >> 5;
  int wr = w >> 2, wc = w & 3;

  int flat = blockIdx.y * gridDim.x + blockIdx.x;
  {
    int nwg = gridDim.x * gridDim.y;
    int q = nwg >> 3, r = nwg & 7, xc = flat & 7, s = flat >> 3;
    flat = (xc < r ? xc * (q + 1) : r * (q + 1) + (xc - r) * q) + s;
  }
  int bm = flat % gridDim.x, bn = flat / gridDim.x;
  int m0 = bm * 256, n0 = bn * 256;

  int row0 = tid >> 3;
  int uc0 = (tid & 7) ^ (row0 & 7);
  int offg = row0 * K + uc0 * 8;
  const u16* aB = A + (size_t)m0 * K;
  const u16* bB = Bt + (size_t)n0 * K;

  auto stA = [&](int kt, int half) {
    const u16* g = aB + (size_t)half * 128 * K + kt * 64 + offg;
    u16* l = AsU + (((kt & 1) * 2 + half) << 13) + w * 512;
    gload_lds16(g, l);
    gload_lds16(g + 64 * K, l + 4096);
  };
  auto stB = [&](int kt, int half) {
    const u16* g = bB + (size_t)half * 128 * K + kt * 64 + offg;
    u16* l = BsU + (((kt & 1) * 2 + half) << 13) + w * 512;
    gload_lds16(g, l);
    gload_lds16(g + 64 * K, l + 4096);
  };

  int brow0 = (wc & 1) * 64 + l31;    // tc adds 32

  short8 aflo[2][4], afhi[2][4], bf[2][4];

  auto rd_aflo = [&](int slot) {
    const u16* sA = AsU + ((slot * 2 + wr) << 13);
    #pragma unroll
    for (int tr = 0; tr < 2; tr++)
      #pragma unroll
      for (int ks = 0; ks < 4; ks++) {
        int row = tr * 32 + l31;
        aflo[tr][ks] = *(const short8*)(sA + row * 64 + (((ks * 2 + lh) ^ (row & 7))) * 8);
      }
  };
  auto rd_afhi = [&](int slot) {
    const u16* sA = AsU + ((slot * 2 + wr) << 13);
    #pragma unroll
    for (int tr = 0; tr < 2; tr++)
      #pragma unroll
      for (int ks = 0; ks < 4; ks++) {
        int row = (tr + 2) * 32 + l31;
        afhi[tr][ks] = *(const short8*)(sA + row * 64 + (((ks * 2 + lh) ^ (row & 7))) * 8);
      }
  };
  auto rd_bf = [&](int slot) {
    const u16* sB = BsU + ((slot * 2 + (wc >> 1)) << 13);
    #pragma unroll
    for (int tc = 0; tc < 2; tc++)
      #pragma unroll
      for (int ks = 0; ks < 4; ks++) {
        int row = brow0 + tc * 32;
        bf[tc][ks] = *(const short8*)(sB + row * 64 + (((ks * 2 + lh) ^ (row & 7))) * 8);
      }
  };

  f32x16 acc[4][2] = {};

  stB(0, 0); stB(0, 1); stA(0, 0); stA(0, 1); stB(1, 0); stB(1, 1);
  VMC(4);
  BARS;
  rd_aflo(0);

  for (int kt = 0; kt < NK; ++kt) {
    int slot = kt & 1;
    // ---- PA: issue bf(8)+afhi(8); LGKM(8); stage A(kt+1); MFMA tr{0,1} ----
    rd_bf(slot);
    rd_afhi(slot);
    LGKM(8);
    BARS;
    if (kt + 1 < NK) { stA(kt + 1, 0); stA(kt + 1, 1); }
    __builtin_amdgcn_s_setprio(1);
    #pragma unroll
    for (int ks = 0; ks < 4; ks++)
      #pragma unroll
      for (int tr = 0; tr < 2; tr++)
        #pragma unroll
        for (int tc = 0; tc < 2; tc++)
          acc[tr][tc] = __builtin_amdgcn_mfma_f32_32x32x16_bf16(aflo[tr][ks], bf[tc][ks], acc[tr][tc], 0, 0, 0);
    __builtin_amdgcn_s_setprio(0);
    // ---- PB: stage B(kt+2); VMC(4); issue aflo(kt+1); LGKM(8); MFMA tr{2,3} ----
    if (kt + 2 < NK) { stB(kt + 2, 0); stB(kt + 2, 1); VMC(4); }
    else if (kt + 1 < NK) { VMC(0); }
    BARS;
    if (kt + 1 < NK) {
      rd_aflo((kt + 1) & 1);
      LGKM(8);
    } else {
      LGKM(0);
    }
    __builtin_amdgcn_s_setprio(1);
    #pragma unroll
    for (int ks = 0; ks < 4; ks++)
      #pragma unroll
      for (int tr = 0; tr < 2; tr++)
        #pragma unroll
        for (int tc = 0; tc < 2; tc++)
          acc[tr + 2][tc] = __builtin_amdgcn_mfma_f32_32x32x16_bf16(afhi[tr][ks], bf[tc][ks], acc[tr + 2][tc], 0, 0, 0);
    __builtin_amdgcn_s_setprio(0);
  }

  // ---- epilogue: LDS-transposed coalesced f32 write (2 passes of 128 rows) ----
  {
    float* lf = (float*)lds;
    #pragma unroll
    for (int pass = 0; pass < 2; pass++) {
      BARS;
      if (wr == pass) {
        #pragma unroll
        for (int tc = 0; tc < 2; tc++) {
          int col = wc * 64 + tc * 32 + l31;
          #pragma unroll
          for (int tr = 0; tr < 4; tr++)
            #pragma unroll
            for (int reg = 0; reg < 16; reg++) {
              int rl = tr * 32 + (reg & 3) + 8 * (reg >> 2) + 4 * lh;
              lf[rl * 256 + (col ^ (((rl >> 2) & 1) << 4))] = acc[tr][tc][reg];
            }
        }
      }
      BARS;
      #pragma unroll
      for (int j = 0; j < 16; j++) {
        int i4 = j * 2048 + tid * 4;
        int row = i4 >> 8;
        int col4 = i4 & 255;
        f32x4 v = *(const f32x4*)(lf + row * 256 + (col4 ^ (((row >> 2) & 1) << 4)));
        *(f32x4*)(outf + (size_t)(m0 + pass * 128 + row) * N + n0 + col4) = v;
      }
    }
  }
}

// ---------------- flash attention: no-max softmax, deferred l, balanced qb mapping ----------------
__global__ __launch_bounds__(512) void attnk(const u16* __restrict__ qkv, const u16* __restrict__ vt,
                                             u16* __restrict__ ao) {
  __shared__ u16 Plds[8][16][72];
  __shared__ float Cacc[4][64][16];
  __shared__ float Cl[4][64][4];
  int bid = blockIdx.x;
  int hh = bid >> 5;
  int qb = (bid & 256) ? (31 - (bid & 31)) : (bid & 31);
  int tid = threadIdx.x, l = tid & 63, w = tid >> 6;
  int w4 = w & 3, ishi = w >> 2;
  int lr = l & 15, lg = l >> 4;
  int qr0 = qb * 64 + w4 * 16;
  const u16* qbase = qkv + (size_t)(qr0 + lr) * (3 * Dc) + hh * HDc + lg * 8;
  short8 aq0 = *(const short8*)qbase;
  short8 aq1 = *(const short8*)(qbase + 32);
  f32x4 acco[4] = {};
  float rs[4] = {0.0f, 0.0f, 0.0f, 0.0f};
  int nkb = (qr0 + 79) >> 6;
  int half = nkb >> 1;
  int klo = ishi ? half : 0;
  int khi = ishi ? nkb : half;
  const float cl2 = 0.125f * 1.44269504088896f;
  for (int kb = klo; kb < khi; kb++) {
    int kk0 = kb * 64;
    float sv[4][4];
    bool msk = (kb == nkb - 1);
    #pragma unroll
    for (int st = 0; st < 4; st++) {
      int kt0 = kk0 + st * 16;
      const u16* kbase = qkv + (size_t)(kt0 + lr) * (3 * Dc) + Dc + hh * HDc + lg * 8;
      short8 bk0 = *(const short8*)kbase;
      short8 bk1 = *(const short8*)(kbase + 32);
      f32x4 s = {};
      s = __builtin_amdgcn_mfma_f32_16x16x32_bf16(aq0, bk0, s, 0, 0, 0);
      s = __builtin_amdgcn_mfma_f32_16x16x32_bf16(aq1, bk1, s, 0, 0, 0);
      if (msk) {
        int gcol = kt0 + lr;
        #pragma unroll
        for (int r = 0; r < 4; r++) {
          int grow = qr0 + lg * 4 + r;
          sv[st][r] = (gcol <= grow) ? s[r] * cl2 : -__builtin_inff();
        }
      } else {
        #pragma unroll
        for (int r = 0; r < 4; r++) sv[st][r] = s[r] * cl2;
      }
    }
    #pragma unroll
    for (int st = 0; st < 4; st++) {
      #pragma unroll
      for (int r = 0; r < 4; r++) {
        float p = __builtin_amdgcn_exp2f(fminf(sv[st][r], 45.0f));
        sv[st][r] = p;
        rs[r] += p;
      }
    }
    #pragma unroll
    for (int st = 0; st < 4; st++) {
      #pragma unroll
      for (int r = 0; r < 4; r++) Plds[w][lg * 4 + r][st * 16 + lr] = f2bf(sv[st][r]);
    }
    short8 pa0 = *(const short8*)&Plds[w][lr][lg * 8];
    short8 pa1 = *(const short8*)&Plds[w][lr][32 + lg * 8];
    #pragma unroll
    for (int nt = 0; nt < 4; nt++) {
      const u16* vbase = vt + (size_t)(hh * HDc + nt * 16 + lr) * Tc + kk0 + lg * 8;
      short8 bv0 = *(const short8*)vbase;
      short8 bv1 = *(const short8*)(vbase + 32);
      acco[nt] = __builtin_amdgcn_mfma_f32_16x16x32_bf16(pa0, bv0, acco[nt], 0, 0, 0);
      acco[nt] = __builtin_amdgcn_mfma_f32_16x16x32_bf16(pa1, bv1, acco[nt], 0, 0, 0);
    }
  }
  #pragma unroll
  for (int off = 1; off < 16; off <<= 1) {
    #pragma unroll
    for (int r = 0; r < 4; r++) rs[r] += __shfl_xor(rs[r], off);
  }
  if (ishi) {
    #pragma unroll
    for (int nt = 0; nt < 4; nt++)
      #pragma unroll
      for (int r = 0; r < 4; r++) Cacc[w4][l][nt * 4 + r] = acco[nt][r];
    #pragma unroll
    for (int r = 0; r < 4; r++) Cl[w4][l][r] = rs[r];
  }
  __syncthreads();
  if (!ishi) {
    float linv[4];
    #pragma unroll
    for (int r = 0; r < 4; r++) linv[r] = 1.0f / (rs[r] + Cl[w4][l][r]);
    #pragma unroll
    for (int nt = 0; nt < 4; nt++) {
      #pragma unroll
      for (int r = 0; r < 4; r++) {
        float val = (acco[nt][r] + Cacc[w4][l][nt * 4 + r]) * linv[r];
        ao[(size_t)(qr0 + lg * 4 + r) * Dc + hh * HDc + nt * 16 + lr] = f2bf(val);
      }
    }
  }
}

extern "C" void kernel_launch(void* const* d_in, const int* in_sizes, int n_in,
                              void* d_out, int out_size, void* d_ws, size_t ws_size,
                              hipStream_t stream) {
  const int*   ids   = (const int*)d_in[0];
  const float* te    = (const float*)d_in[1];
  const float* pe    = (const float*)d_in[2];
  const float* qkv_w = (const float*)d_in[3];
  const float* qkv_b = (const float*)d_in[4];
  const float* out_w = (const float*)d_in[5];
  const float* out_b = (const float*)d_in[6];
  const float* ln1_w = (const float*)d_in[7];
  const float* ln1_b = (const float*)d_in[8];
  const float* ln2_w = (const float*)d_in[9];
  const float* ln2_b = (const float*)d_in[10];
  const float* up_w  = (const float*)d_in[11];
  const float* up_b  = (const float*)d_in[12];
  const float* dn_w  = (const float*)d_in[13];
  const float* dn_b  = (const float*)d_in[14];
  const float* lnf_w = (const float*)d_in[15];
  const float* lnf_b = (const float*)d_in[16];
  float* logits = (float*)d_out;

  char* ws = (char*)d_ws;
  size_t off = 0;
  auto alloc = [&](size_t bytes) { void* p = ws + off; off += (bytes + 255) & ~(size_t)255; return p; };
  float* x    = (float*)alloc((size_t)Tc * Dc * 4);
  u16* hbuf   = (u16*)alloc((size_t)Tc * Dc * 2);
  u16* qkvb   = (u16*)alloc((size_t)Tc * 3 * Dc * 2);
  u16* aob    = (u16*)alloc((size_t)Tc * Dc * 2);
  u16* ubuf   = (u16*)alloc((size_t)Tc * DFc * 2);
  u16* vtb    = (u16*)alloc((size_t)Dc * Tc * 2);
  u16* tebf   = (u16*)alloc((size_t)Vc * Dc * 2);
  u16* qkvT   = (u16*)alloc((size_t)3 * Dc * Dc * 2);
  u16* outT   = (u16*)alloc((size_t)Dc * Dc * 2);
  u16* upT    = (u16*)alloc((size_t)DFc * Dc * 2);
  u16* dnT    = (u16*)alloc((size_t)Dc * DFc * 2);
  float* pbuf = (float*)alloc((size_t)4 * Tc * Dc * 4);

  castk<<<Vc * Dc / 1024, 256, 0, stream>>>(te, tebf);
  embedln<<<Tc, 256, 0, stream>>>(ids, te, pe, ln1_w, ln1_b, x, hbuf);

  for (int i = 0; i < Lc; i++) {
    transpose4<<<12288, 256, 0, stream>>>(
        qkv_w + (size_t)i * Dc * 3 * Dc, out_w + (size_t)i * Dc * Dc,
        up_w + (size_t)i * Dc * DFc, dn_w + (size_t)i * DFc * Dc,
        qkvT, outT, upT, dnT);

    gemm128m<5><<<dim3(3 * Dc / 128, Tc / 128, 1), 256, 0, stream>>>(
        hbuf, qkvT, qkv_b + (size_t)i * 3 * Dc, qkvb, (float*)vtb, Tc, 3 * Dc, Dc, Dc);
    attnk<<<512, 512, 0, stream>>>(qkvb, vtb, aob);
    gemm128m<4><<<dim3(Dc / 128, Tc / 128, 2), 256, 0, stream>>>(
        aob, outT, nullptr, nullptr, pbuf, Tc, Dc, Dc, Dc / 2);
    combineln<2><<<Tc, 256, 0, stream>>>(x, pbuf, out_b + (size_t)i * Dc,
                                         ln2_w + (size_t)i * Dc, ln2_b + (size_t)i * Dc, hbuf);
    gemm128m<1><<<dim3(DFc / 128, Tc / 128, 1), 256, 0, stream>>>(
        hbuf, upT, up_b + (size_t)i * DFc, ubuf, nullptr, Tc, DFc, Dc, Dc);
    gemm128m<4><<<dim3(Dc / 128, Tc / 128, 4), 256, 0, stream>>>(
        ubuf, dnT, nullptr, nullptr, pbuf, Tc, Dc, DFc, DFc / 4);
    if (i < Lc - 1)
      combineln<4><<<Tc, 256, 0, stream>>>(x, pbuf, dn_b + (size_t)i * Dc,
                                           ln1_w + (size_t)(i + 1) * Dc, ln1_b + (size_t)(i + 1) * Dc, hbuf);
    else
      combineln<4><<<Tc, 256, 0, stream>>>(x, pbuf, dn_b + (size_t)i * Dc, lnf_w, lnf_b, hbuf);
  }

  gemm256<<<dim3(Tc / 256, Vc / 256), 512, 0, stream>>>(hbuf, tebf, logits, Tc, Vc, Dc);
}

// Round 17
// 933.216 us; speedup vs baseline: 1.0696x; 1.0696x over previous
//
#include <hip/hip_runtime.h>

typedef __attribute__((ext_vector_type(8))) short short8;
typedef __attribute__((ext_vector_type(4))) short short4v;
typedef __attribute__((ext_vector_type(4))) float f32x4;
typedef unsigned short u16;

#define Lc 4
#define Dc 1024
#define Hc 16
#define HDc 64
#define DFc 4096
#define Vc 32000
#define Tc 2048

__device__ __forceinline__ u16 f2bf(float f) {
  union { float f; unsigned u; } v; v.f = f;
  return (u16)((v.u + 0x7FFFu + ((v.u >> 16) & 1u)) >> 16);
}

__device__ __forceinline__ void gload_lds16(const u16* g, u16* l) {
  __builtin_amdgcn_global_load_lds(
      (const __attribute__((address_space(1))) unsigned int*)(g),
      (__attribute__((address_space(3))) unsigned int*)(l), 16, 0, 0);
}

#define BARS do { __builtin_amdgcn_s_barrier(); __builtin_amdgcn_sched_barrier(0); } while (0)
#define LGKM(n) do { asm volatile("s_waitcnt lgkmcnt(" #n ")" ::: "memory"); __builtin_amdgcn_sched_barrier(0); } while (0)
#define VMC(n) do { asm volatile("s_waitcnt vmcnt(" #n ")" ::: "memory"); __builtin_amdgcn_sched_barrier(0); } while (0)

// ---------------- f32 -> bf16 cast ----------------
__global__ __launch_bounds__(256) void castk(const float* __restrict__ in, u16* __restrict__ out) {
  size_t i = ((size_t)blockIdx.x * 256 + threadIdx.x) * 4;
  float4 v = *(const float4*)(in + i);
  short4v o; o[0] = f2bf(v.x); o[1] = f2bf(v.y); o[2] = f2bf(v.z); o[3] = f2bf(v.w);
  *(short4v*)(out + i) = o;
}

// ---------------- fused embedding + layernorm ----------------
__global__ __launch_bounds__(256) void embedln(const int* __restrict__ ids, const float* __restrict__ te,
                                               const float* __restrict__ pe, const float* __restrict__ w,
                                               const float* __restrict__ b, float* __restrict__ x,
                                               u16* __restrict__ out) {
  int t = blockIdx.x, tid = threadIdx.x;
  int id = ids[t];
  float4 a = *(const float4*)(te + (size_t)id * Dc + tid * 4);
  float4 p = *(const float4*)(pe + (size_t)t * Dc + tid * 4);
  float4 v; v.x = a.x + p.x; v.y = a.y + p.y; v.z = a.z + p.z; v.w = a.w + p.w;
  size_t i = (size_t)t * Dc + tid * 4;
  *(float4*)(x + i) = v;
  float s = v.x + v.y + v.z + v.w;
  float q = v.x * v.x + v.y * v.y + v.z * v.z + v.w * v.w;
  #pragma unroll
  for (int off = 1; off < 64; off <<= 1) { s += __shfl_xor(s, off); q += __shfl_xor(q, off); }
  __shared__ float red[8];
  if ((tid & 63) == 0) { red[tid >> 6] = s; red[4 + (tid >> 6)] = q; }
  __syncthreads();
  s = red[0] + red[1] + red[2] + red[3];
  q = red[4] + red[5] + red[6] + red[7];
  float mean = s * (1.0f / Dc);
  float rstd = rsqrtf(q * (1.0f / Dc) - mean * mean + 1e-5f);
  float4 wv = *(const float4*)(w + tid * 4);
  float4 bv = *(const float4*)(b + tid * 4);
  out[i + 0] = f2bf((v.x - mean) * rstd * wv.x + bv.x);
  out[i + 1] = f2bf((v.y - mean) * rstd * wv.y + bv.y);
  out[i + 2] = f2bf((v.z - mean) * rstd * wv.z + bv.z);
  out[i + 3] = f2bf((v.w - mean) * rstd * wv.w + bv.w);
}

// ---------------- fused split-K combine + layernorm ----------------
template<int SK>
__global__ __launch_bounds__(256) void combineln(float* __restrict__ x, const float* __restrict__ p,
                                                 const float* __restrict__ bias, const float* __restrict__ w,
                                                 const float* __restrict__ b, u16* __restrict__ out) {
  int t = blockIdx.x, tid = threadIdx.x;
  size_t i = (size_t)t * Dc + tid * 4;
  float4 v = *(const float4*)(x + i);
  #pragma unroll
  for (int s = 0; s < SK; s++) {
    float4 q2 = *(const float4*)(p + (size_t)s * Tc * Dc + i);
    v.x += q2.x; v.y += q2.y; v.z += q2.z; v.w += q2.w;
  }
  float4 bb = *(const float4*)(bias + tid * 4);
  v.x += bb.x; v.y += bb.y; v.z += bb.z; v.w += bb.w;
  *(float4*)(x + i) = v;
  float s = v.x + v.y + v.z + v.w;
  float q = v.x * v.x + v.y * v.y + v.z * v.z + v.w * v.w;
  #pragma unroll
  for (int off = 1; off < 64; off <<= 1) { s += __shfl_xor(s, off); q += __shfl_xor(q, off); }
  __shared__ float red[8];
  if ((tid & 63) == 0) { red[tid >> 6] = s; red[4 + (tid >> 6)] = q; }
  __syncthreads();
  s = red[0] + red[1] + red[2] + red[3];
  q = red[4] + red[5] + red[6] + red[7];
  float mean = s * (1.0f / Dc);
  float rstd = rsqrtf(q * (1.0f / Dc) - mean * mean + 1e-5f);
  float4 wv = *(const float4*)(w + tid * 4);
  float4 bv = *(const float4*)(b + tid * 4);
  out[i + 0] = f2bf((v.x - mean) * rstd * wv.x + bv.x);
  out[i + 1] = f2bf((v.y - mean) * rstd * wv.y + bv.y);
  out[i + 2] = f2bf((v.z - mean) * rstd * wv.z + bv.z);
  out[i + 3] = f2bf((v.w - mean) * rstd * wv.w + bv.w);
}

// ---------------- merged per-layer weight transpose ----------------
__global__ __launch_bounds__(256) void transpose4(const float* __restrict__ qw, const float* __restrict__ ow,
                                                  const float* __restrict__ uw, const float* __restrict__ dw,
                                                  u16* __restrict__ qT, u16* __restrict__ oT,
                                                  u16* __restrict__ uT, u16* __restrict__ dT) {
  __shared__ float tl[32][33];
  int id = blockIdx.x;
  const float* in; u16* out; int R, C, t;
  if (id < 3072)      { in = qw; out = qT; R = Dc;  C = 3 * Dc; t = id; }
  else if (id < 4096) { in = ow; out = oT; R = Dc;  C = Dc;     t = id - 3072; }
  else if (id < 8192) { in = uw; out = uT; R = Dc;  C = DFc;    t = id - 4096; }
  else                { in = dw; out = dT; R = DFc; C = Dc;     t = id - 8192; }
  int tilesX = C >> 5;
  int c0 = (t % tilesX) * 32, r0 = (t / tilesX) * 32;
  int lx = threadIdx.x & 31, ly = threadIdx.x >> 5;
  #pragma unroll
  for (int i = ly; i < 32; i += 8) tl[i][lx] = in[(size_t)(r0 + i) * C + c0 + lx];
  __syncthreads();
  #pragma unroll
  for (int i = ly; i < 32; i += 8) out[(size_t)(c0 + i) * R + r0 + lx] = f2bf(tl[lx][i]);
}

// ---------------- 128x128 layer GEMM, BK=64, 2-phase-merged (R13 proven config) ----------------
// PA: {read af01(4)+bf all(8); stage A(kt+1); bar; lgkm0; 16 MFMA m01xN; bar}
// PB: {read af23(4); stage B(kt+2); VMC(4) retires tile kt+1; bar; lgkm0; 16 MFMA m23xN; bar}
// EPI: 0 bias->bf16 | 1 bias+silu->bf16 | 4 f32 partial (split-K) | 5 qkv fused (V->vt transposed)
template<int EPI>
__global__ __launch_bounds__(256) void gemm128m(
    const u16* __restrict__ A, const u16* __restrict__ Bt, const float* __restrict__ bias,
    u16* __restrict__ outb, float* __restrict__ outf, int M, int N, int K, int KS) {
  __shared__ __align__(16) u16 lds[32768];
  u16* As = lds;
  u16* Bs = lds + 16384;
  const int NK = KS >> 6;

  int tid = threadIdx.x;
  int w = tid >> 6, lane = tid & 63;
  int lr = lane & 15, lg = lane >> 4;
  int wr = w >> 1, wc = w & 1;

  int m0 = blockIdx.y * 128, n0 = blockIdx.x * 128;
  int kbase = blockIdx.z * KS;

  int offg[4];
  #pragma unroll
  for (int j = 0; j < 4; j++) {
    int p = tid + j * 256;
    int row = p >> 3;
    int uc = (p & 7) ^ (row & 7);
    offg[j] = row * K + uc * 8;
  }
  const u16* aB = A + (size_t)m0 * K + kbase;
  const u16* bB = Bt + (size_t)n0 * K + kbase;

  auto stA = [&](int kt) {
    u16* l = As + ((kt & 1) << 13) + w * 512;
    #pragma unroll
    for (int j = 0; j < 4; j++)
      gload_lds16(aB + kt * 64 + offg[j], l + j * 2048);
  };
  auto stB = [&](int kt) {
    u16* l = Bs + ((kt & 1) << 13) + w * 512;
    #pragma unroll
    for (int j = 0; j < 4; j++)
      gload_lds16(bB + kt * 64 + offg[j], l + j * 2048);
  };

  int colx0 = ((0 * 4 + lg) ^ (lr & 7)) * 8;
  int colx1 = ((1 * 4 + lg) ^ (lr & 7)) * 8;
  int abase = (wr * 64 + lr) * 64;
  int bbase = (wc * 64 + lr) * 64;

  f32x4 acc[4][4] = {};

  // prologue: B0(4), A0(4), B1(4); VMC(4) retires B0+A0, leaves B1 in flight
  stB(0); stA(0); stB(1);
  VMC(4);
  BARS;

  for (int kt = 0; kt < NK; ++kt) {
    const u16* sA = As + ((kt & 1) << 13);
    const u16* sB = Bs + ((kt & 1) << 13);
    short8 af[4][2], bf[4][2];

    // ---- PA: read af01 + all bf; stage A(kt+1); MFMA m01 x n0123 ----
    #pragma unroll
    for (int m = 0; m < 2; m++) {
      af[m][0] = *(const short8*)(sA + abase + m * 1024 + colx0);
      af[m][1] = *(const short8*)(sA + abase + m * 1024 + colx1);
    }
    #pragma unroll
    for (int n = 0; n < 4; n++) {
      bf[n][0] = *(const short8*)(sB + bbase + n * 1024 + colx0);
      bf[n][1] = *(const short8*)(sB + bbase + n * 1024 + colx1);
    }
    if (kt + 1 < NK) stA(kt + 1);
    BARS;
    LGKM(0);
    __builtin_amdgcn_s_setprio(1);
    #pragma unroll
    for (int m = 0; m < 2; m++)
      #pragma unroll
      for (int n = 0; n < 4; n++)
        #pragma unroll
        for (int ks = 0; ks < 2; ks++)
          acc[m][n] = __builtin_amdgcn_mfma_f32_16x16x32_bf16(af[m][ks], bf[n][ks], acc[m][n], 0, 0, 0);
    __builtin_amdgcn_s_setprio(0);
    BARS;

    // ---- PB: read af23; stage B(kt+2); VMC(4); MFMA m23 x n0123 ----
    #pragma unroll
    for (int m = 2; m < 4; m++) {
      af[m][0] = *(const short8*)(sA + abase + m * 1024 + colx0);
      af[m][1] = *(const short8*)(sA + abase + m * 1024 + colx1);
    }
    if (kt + 2 < NK) { stB(kt + 2); VMC(4); }
    else if (kt + 1 < NK) { VMC(0); }
    BARS;
    LGKM(0);
    __builtin_amdgcn_s_setprio(1);
    #pragma unroll
    for (int m = 2; m < 4; m++)
      #pragma unroll
      for (int n = 0; n < 4; n++)
        #pragma unroll
        for (int ks = 0; ks < 2; ks++)
          acc[m][n] = __builtin_amdgcn_mfma_f32_16x16x32_bf16(af[m][ks], bf[n][ks], acc[m][n], 0, 0, 0);
    __builtin_amdgcn_s_setprio(0);
    BARS;
  }

  float* op = outf + (EPI == 4 ? (size_t)blockIdx.z * M * N : 0);
  u16* vtp = (u16*)outf;  // EPI==5: vt buffer
  #pragma unroll
  for (int n = 0; n < 4; n++) {
    int gn = n0 + wc * 64 + n * 16 + lr;
    float bv = (EPI == 0 || EPI == 1 || EPI == 5) ? bias[gn] : 0.0f;
    #pragma unroll
    for (int m = 0; m < 4; m++) {
      if (EPI == 5 && gn >= 2 * Dc) {
        int gmb = m0 + wr * 64 + m * 16 + lg * 4;
        short4v o;
        #pragma unroll
        for (int r = 0; r < 4; r++) o[r] = (short)f2bf(acc[m][n][r] + bv);
        *(short4v*)(vtp + (size_t)(gn - 2 * Dc) * Tc + gmb) = o;
      } else {
        #pragma unroll
        for (int r = 0; r < 4; r++) {
          int gm = m0 + wr * 64 + m * 16 + lg * 4 + r;
          float v = acc[m][n][r] + bv;
          size_t idx = (size_t)gm * N + gn;
          if (EPI == 0 || EPI == 5) outb[idx] = f2bf(v);
          else if (EPI == 1) outb[idx] = f2bf(v / (1.0f + __expf(-v)));
          else op[idx] = v;
        }
      }
    }
  }
}

// ---------------- 256x256 logits GEMM, 2-phase counted-lgkm + coalesced epilogue (R15 proven) ----------------
__global__ __launch_bounds__(512) void gemm256(const u16* __restrict__ A, const u16* __restrict__ Bt,
                                               float* __restrict__ outf, int M, int N, int K) {
  __shared__ __align__(16) u16 lds[65536];
  u16* AsU = lds;
  u16* BsU = lds + 32768;
  const int NK = K >> 6;

  int tid = threadIdx.x;
  int w = tid >> 6, lane = tid & 63;
  int lr = lane & 15, lg = lane >> 4;
  int wr = w >> 2, wc = w & 3;

  int flat = blockIdx.y * gridDim.x + blockIdx.x;
  {
    int nwg = gridDim.x * gridDim.y;
    int q = nwg >> 3, r = nwg & 7, xc = flat & 7, s = flat >> 3;
    flat = (xc < r ? xc * (q + 1) : r * (q + 1) + (xc - r) * q) + s;
  }
  int bm = flat % gridDim.x, bn = flat / gridDim.x;
  int m0 = bm * 256, n0 = bn * 256;

  int row0 = tid >> 3;
  int uc0 = (tid & 7) ^ (row0 & 7);
  int offg = row0 * K + uc0 * 8;
  const u16* aB = A + (size_t)m0 * K;
  const u16* bB = Bt + (size_t)n0 * K;

  auto stA = [&](int kt, int half) {
    const u16* g = aB + (size_t)half * 128 * K + kt * 64 + offg;
    u16* l = AsU + (((kt & 1) * 2 + half) << 13) + w * 512;
    gload_lds16(g, l);
    gload_lds16(g + 64 * K, l + 4096);
  };
  auto stB = [&](int kt, int half) {
    const u16* g = bB + (size_t)half * 128 * K + kt * 64 + offg;
    u16* l = BsU + (((kt & 1) * 2 + half) << 13) + w * 512;
    gload_lds16(g, l);
    gload_lds16(g + 64 * K, l + 4096);
  };

  int colx0 = ((0 * 4 + lg) ^ (lr & 7)) * 8;
  int colx1 = ((1 * 4 + lg) ^ (lr & 7)) * 8;
  int arow = lr * 64;
  int brow = ((wc & 1) * 64 + lr) * 64;

  short8 af0[4][2], af1[4][2], bf0[2][2], bf1[2][2];

  auto rd_af_lo = [&](int slot) {
    const u16* sA = AsU + ((slot * 2 + wr) << 13);
    #pragma unroll
    for (int m = 0; m < 4; m++) {
      af0[m][0] = *(const short8*)(sA + arow + m * 1024 + colx0);
      af0[m][1] = *(const short8*)(sA + arow + m * 1024 + colx1);
    }
  };
  auto rd_af_hi = [&](int slot) {
    const u16* sA = AsU + ((slot * 2 + wr) << 13);
    #pragma unroll
    for (int m = 0; m < 4; m++) {
      af1[m][0] = *(const short8*)(sA + arow + (m + 4) * 1024 + colx0);
      af1[m][1] = *(const short8*)(sA + arow + (m + 4) * 1024 + colx1);
    }
  };
  auto rd_bf = [&](int slot) {
    const u16* sB = BsU + ((slot * 2 + (wc >> 1)) << 13);
    #pragma unroll
    for (int n = 0; n < 2; n++) {
      bf0[n][0] = *(const short8*)(sB + brow + n * 1024 + colx0);
      bf0[n][1] = *(const short8*)(sB + brow + n * 1024 + colx1);
      bf1[n][0] = *(const short8*)(sB + brow + (n + 2) * 1024 + colx0);
      bf1[n][1] = *(const short8*)(sB + brow + (n + 2) * 1024 + colx1);
    }
  };

  f32x4 acc[8][4] = {};

  // prologue: stage B0,A0,B1; VMC(4) retires B0+A0 (B1 in flight); issue af_lo(0)
  stB(0, 0); stB(0, 1); stA(0, 0); stA(0, 1); stB(1, 0); stB(1, 1);
  VMC(4);
  BARS;
  rd_af_lo(0);

  for (int kt = 0; kt < NK; ++kt) {
    int slot = kt & 1;
    // ---- PA ----
    rd_bf(slot);
    rd_af_hi(slot);
    LGKM(8);
    BARS;
    if (kt + 1 < NK) { stA(kt + 1, 0); stA(kt + 1, 1); }
    __builtin_amdgcn_s_setprio(1);
    #pragma unroll
    for (int m = 0; m < 4; m++)
      #pragma unroll
      for (int n = 0; n < 2; n++)
        #pragma unroll
        for (int ks = 0; ks < 2; ks++)
          acc[m][n] = __builtin_amdgcn_mfma_f32_16x16x32_bf16(af0[m][ks], bf0[n][ks], acc[m][n], 0, 0, 0);
    #pragma unroll
    for (int m = 0; m < 4; m++)
      #pragma unroll
      for (int n = 0; n < 2; n++)
        #pragma unroll
        for (int ks = 0; ks < 2; ks++)
          acc[m][n + 2] = __builtin_amdgcn_mfma_f32_16x16x32_bf16(af0[m][ks], bf1[n][ks], acc[m][n + 2], 0, 0, 0);
    __builtin_amdgcn_s_setprio(0);
    // ---- PB ----
    if (kt + 2 < NK) { stB(kt + 2, 0); stB(kt + 2, 1); VMC(4); }
    else if (kt + 1 < NK) { VMC(0); }
    BARS;
    if (kt + 1 < NK) {
      rd_af_lo((kt + 1) & 1);
      LGKM(8);
    } else {
      LGKM(0);
    }
    __builtin_amdgcn_s_setprio(1);
    #pragma unroll
    for (int m = 0; m < 4; m++)
      #pragma unroll
      for (int n = 0; n < 2; n++)
        #pragma unroll
        for (int ks = 0; ks < 2; ks++)
          acc[m + 4][n] = __builtin_amdgcn_mfma_f32_16x16x32_bf16(af1[m][ks], bf0[n][ks], acc[m + 4][n], 0, 0, 0);
    #pragma unroll
    for (int m = 0; m < 4; m++)
      #pragma unroll
      for (int n = 0; n < 2; n++)
        #pragma unroll
        for (int ks = 0; ks < 2; ks++)
          acc[m + 4][n + 2] = __builtin_amdgcn_mfma_f32_16x16x32_bf16(af1[m][ks], bf1[n][ks], acc[m + 4][n + 2], 0, 0, 0);
    __builtin_amdgcn_s_setprio(0);
  }

  // ---- epilogue: LDS-transposed coalesced f32 write ----
  {
    float* lf = (float*)lds;
    #pragma unroll
    for (int pass = 0; pass < 2; pass++) {
      BARS;
      if (wr == pass) {
        #pragma unroll
        for (int n = 0; n < 4; n++) {
          int col = wc * 64 + n * 16 + lr;
          #pragma unroll
          for (int m = 0; m < 8; m++)
            #pragma unroll
            for (int r = 0; r < 4; r++) {
              int rl = m * 16 + lg * 4 + r;
              lf[rl * 256 + (col ^ (((rl >> 2) & 1) << 4))] = acc[m][n][r];
            }
        }
      }
      BARS;
      #pragma unroll
      for (int j = 0; j < 16; j++) {
        int i4 = j * 2048 + tid * 4;
        int row = i4 >> 8;
        int col4 = i4 & 255;
        f32x4 v = *(const f32x4*)(lf + row * 256 + (col4 ^ (((row >> 2) & 1) << 4)));
        *(f32x4*)(outf + (size_t)(m0 + pass * 128 + row) * N + n0 + col4) = v;
      }
    }
  }
}

// ---------------- flash attention: no-max softmax, deferred l, balanced qb mapping ----------------
__global__ __launch_bounds__(512) void attnk(const u16* __restrict__ qkv, const u16* __restrict__ vt,
                                             u16* __restrict__ ao) {
  __shared__ u16 Plds[8][16][72];
  __shared__ float Cacc[4][64][16];
  __shared__ float Cl[4][64][4];
  int bid = blockIdx.x;
  int hh = bid >> 5;
  int qb = (bid & 256) ? (31 - (bid & 31)) : (bid & 31);
  int tid = threadIdx.x, l = tid & 63, w = tid >> 6;
  int w4 = w & 3, ishi = w >> 2;
  int lr = l & 15, lg = l >> 4;
  int qr0 = qb * 64 + w4 * 16;
  const u16* qbase = qkv + (size_t)(qr0 + lr) * (3 * Dc) + hh * HDc + lg * 8;
  short8 aq0 = *(const short8*)qbase;
  short8 aq1 = *(const short8*)(qbase + 32);
  f32x4 acco[4] = {};
  float rs[4] = {0.0f, 0.0f, 0.0f, 0.0f};
  int nkb = (qr0 + 79) >> 6;
  int half = nkb >> 1;
  int klo = ishi ? half : 0;
  int khi = ishi ? nkb : half;
  const float cl2 = 0.125f * 1.44269504088896f;
  for (int kb = klo; kb < khi; kb++) {
    int kk0 = kb * 64;
    float sv[4][4];
    bool msk = (kb == nkb - 1);
    #pragma unroll
    for (int st = 0; st < 4; st++) {
      int kt0 = kk0 + st * 16;
      const u16* kbase = qkv + (size_t)(kt0 + lr) * (3 * Dc) + Dc + hh * HDc + lg * 8;
      short8 bk0 = *(const short8*)kbase;
      short8 bk1 = *(const short8*)(kbase + 32);
      f32x4 s = {};
      s = __builtin_amdgcn_mfma_f32_16x16x32_bf16(aq0, bk0, s, 0, 0, 0);
      s = __builtin_amdgcn_mfma_f32_16x16x32_bf16(aq1, bk1, s, 0, 0, 0);
      if (msk) {
        int gcol = kt0 + lr;
        #pragma unroll
        for (int r = 0; r < 4; r++) {
          int grow = qr0 + lg * 4 + r;
          sv[st][r] = (gcol <= grow) ? s[r] * cl2 : -__builtin_inff();
        }
      } else {
        #pragma unroll
        for (int r = 0; r < 4; r++) sv[st][r] = s[r] * cl2;
      }
    }
    #pragma unroll
    for (int st = 0; st < 4; st++) {
      #pragma unroll
      for (int r = 0; r < 4; r++) {
        float p = __builtin_amdgcn_exp2f(fminf(sv[st][r], 45.0f));
        sv[st][r] = p;
        rs[r] += p;
      }
    }
    #pragma unroll
    for (int st = 0; st < 4; st++) {
      #pragma unroll
      for (int r = 0; r < 4; r++) Plds[w][lg * 4 + r][st * 16 + lr] = f2bf(sv[st][r]);
    }
    short8 pa0 = *(const short8*)&Plds[w][lr][lg * 8];
    short8 pa1 = *(const short8*)&Plds[w][lr][32 + lg * 8];
    #pragma unroll
    for (int nt = 0; nt < 4; nt++) {
      const u16* vbase = vt + (size_t)(hh * HDc + nt * 16 + lr) * Tc + kk0 + lg * 8;
      short8 bv0 = *(const short8*)vbase;
      short8 bv1 = *(const short8*)(vbase + 32);
      acco[nt] = __builtin_amdgcn_mfma_f32_16x16x32_bf16(pa0, bv0, acco[nt], 0, 0, 0);
      acco[nt] = __builtin_amdgcn_mfma_f32_16x16x32_bf16(pa1, bv1, acco[nt], 0, 0, 0);
    }
  }
  #pragma unroll
  for (int off = 1; off < 16; off <<= 1) {
    #pragma unroll
    for (int r = 0; r < 4; r++) rs[r] += __shfl_xor(rs[r], off);
  }
  if (ishi) {
    #pragma unroll
    for (int nt = 0; nt < 4; nt++)
      #pragma unroll
      for (int r = 0; r < 4; r++) Cacc[w4][l][nt * 4 + r] = acco[nt][r];
    #pragma unroll
    for (int r = 0; r < 4; r++) Cl[w4][l][r] = rs[r];
  }
  __syncthreads();
  if (!ishi) {
    float linv[4];
    #pragma unroll
    for (int r = 0; r < 4; r++) linv[r] = 1.0f / (rs[r] + Cl[w4][l][r]);
    #pragma unroll
    for (int nt = 0; nt < 4; nt++) {
      #pragma unroll
      for (int r = 0; r < 4; r++) {
        float val = (acco[nt][r] + Cacc[w4][l][nt * 4 + r]) * linv[r];
        ao[(size_t)(qr0 + lg * 4 + r) * Dc + hh * HDc + nt * 16 + lr] = f2bf(val);
      }
    }
  }
}

extern "C" void kernel_launch(void* const* d_in, const int* in_sizes, int n_in,
                              void* d_out, int out_size, void* d_ws, size_t ws_size,
                              hipStream_t stream) {
  const int*   ids   = (const int*)d_in[0];
  const float* te    = (const float*)d_in[1];
  const float* pe    = (const float*)d_in[2];
  const float* qkv_w = (const float*)d_in[3];
  const float* qkv_b = (const float*)d_in[4];
  const float* out_w = (const float*)d_in[5];
  const float* out_b = (const float*)d_in[6];
  const float* ln1_w = (const float*)d_in[7];
  const float* ln1_b = (const float*)d_in[8];
  const float* ln2_w = (const float*)d_in[9];
  const float* ln2_b = (const float*)d_in[10];
  const float* up_w  = (const float*)d_in[11];
  const float* up_b  = (const float*)d_in[12];
  const float* dn_w  = (const float*)d_in[13];
  const float* dn_b  = (const float*)d_in[14];
  const float* lnf_w = (const float*)d_in[15];
  const float* lnf_b = (const float*)d_in[16];
  float* logits = (float*)d_out;

  char* ws = (char*)d_ws;
  size_t off = 0;
  auto alloc = [&](size_t bytes) { void* p = ws + off; off += (bytes + 255) & ~(size_t)255; return p; };
  float* x    = (float*)alloc((size_t)Tc * Dc * 4);
  u16* hbuf   = (u16*)alloc((size_t)Tc * Dc * 2);
  u16* qkvb   = (u16*)alloc((size_t)Tc * 3 * Dc * 2);
  u16* aob    = (u16*)alloc((size_t)Tc * Dc * 2);
  u16* ubuf   = (u16*)alloc((size_t)Tc * DFc * 2);
  u16* vtb    = (u16*)alloc((size_t)Dc * Tc * 2);
  u16* tebf   = (u16*)alloc((size_t)Vc * Dc * 2);
  u16* qkvT   = (u16*)alloc((size_t)3 * Dc * Dc * 2);
  u16* outT   = (u16*)alloc((size_t)Dc * Dc * 2);
  u16* upT    = (u16*)alloc((size_t)DFc * Dc * 2);
  u16* dnT    = (u16*)alloc((size_t)Dc * DFc * 2);
  float* pbuf = (float*)alloc((size_t)4 * Tc * Dc * 4);

  castk<<<Vc * Dc / 1024, 256, 0, stream>>>(te, tebf);
  embedln<<<Tc, 256, 0, stream>>>(ids, te, pe, ln1_w, ln1_b, x, hbuf);

  for (int i = 0; i < Lc; i++) {
    transpose4<<<12288, 256, 0, stream>>>(
        qkv_w + (size_t)i * Dc * 3 * Dc, out_w + (size_t)i * Dc * Dc,
        up_w + (size_t)i * Dc * DFc, dn_w + (size_t)i * DFc * Dc,
        qkvT, outT, upT, dnT);

    gemm128m<5><<<dim3(3 * Dc / 128, Tc / 128, 1), 256, 0, stream>>>(
        hbuf, qkvT, qkv_b + (size_t)i * 3 * Dc, qkvb, (float*)vtb, Tc, 3 * Dc, Dc, Dc);
    attnk<<<512, 512, 0, stream>>>(qkvb, vtb, aob);
    gemm128m<4><<<dim3(Dc / 128, Tc / 128, 2), 256, 0, stream>>>(
        aob, outT, nullptr, nullptr, pbuf, Tc, Dc, Dc, Dc / 2);
    combineln<2><<<Tc, 256, 0, stream>>>(x, pbuf, out_b + (size_t)i * Dc,
                                         ln2_w + (size_t)i * Dc, ln2_b + (size_t)i * Dc, hbuf);
    gemm128m<1><<<dim3(DFc / 128, Tc / 128, 1), 256, 0, stream>>>(
        hbuf, upT, up_b + (size_t)i * DFc, ubuf, nullptr, Tc, DFc, Dc, Dc);
    gemm128m<4><<<dim3(Dc / 128, Tc / 128, 4), 256, 0, stream>>>(
        ubuf, dnT, nullptr, nullptr, pbuf, Tc, Dc, DFc, DFc / 4);
    if (i < Lc - 1)
      combineln<4><<<Tc, 256, 0, stream>>>(x, pbuf, dn_b + (size_t)i * Dc,
                                           ln1_w + (size_t)(i + 1) * Dc, ln1_b + (size_t)(i + 1) * Dc, hbuf);
    else
      combineln<4><<<Tc, 256, 0, stream>>>(x, pbuf, dn_b + (size_t)i * Dc, lnf_w, lnf_b, hbuf);
  }

  gemm256<<<dim3(Tc / 256, Vc / 256), 512, 0, stream>>>(hbuf, tebf, logits, Tc, Vc, Dc);
}